// Round 1
// baseline (978.618 us; speedup 1.0000x reference)
//
#include <hip/hip_runtime.h>
#include <hip/hip_bf16.h>
#include <math.h>

// Problem constants (B=64, N=197, D=768, NH=8, HID=3072).
// fp32 global I/O; bf16 ws intermediates; bf16 weight cache in ws when it fits.
// Large GEMMs (qkv/fc1/wm): 256x256 tile, BK=64, 8-wave, 8-phase counted-vmcnt
// schedule (T2 chunk-XOR swizzle + T3/T4 counted vmcnt(6) + T5 setprio).
// Small-N GEMMs (proj/wa/f2, N=768): proven 128x128 2-barrier kernel (better
// grid packing: 594 blocks vs 150).
#define MROWS (64*197)   // 12608 rows
#define DMODEL 768
#define DHID   3072

typedef __hip_bfloat16 bf16;
using bf16x8 = __attribute__((ext_vector_type(8))) short;  // 8 bf16 (4 VGPRs)
using f32x4  = __attribute__((ext_vector_type(4))) float;  // MFMA accumulator

__device__ __forceinline__ float b2f(bf16 v) { return __bfloat162float(v); }
__device__ __forceinline__ short f2bs(float f) {
    bf16 h = __float2bfloat16(f);
    return *reinterpret_cast<short*>(&h);
}
__device__ __forceinline__ void b8f(bf16x8 v, float* f) {
#pragma unroll
    for (int j = 0; j < 8; ++j)
        f[j] = __uint_as_float(((unsigned int)(unsigned short)v[j]) << 16);
}
__device__ __forceinline__ bf16x8 f8b(const float* f) {
    bf16x8 r;
#pragma unroll
    for (int j = 0; j < 8; ++j) r[j] = f2bs(f[j]);
    return r;
}
__device__ __forceinline__ float gelu_exact(float v) {
    return 0.5f * v * (1.0f + erff(v * 0.70710678118654752f));
}
__device__ __forceinline__ void st1(bf16* p, float v) { *p = __float2bfloat16(v); }
__device__ __forceinline__ void st1(float* p, float v) { *p = v; }

// async global(16B) -> LDS, gfx950 width-16 variant
__device__ __forceinline__ void gl_lds16(const short* g, short* l) {
    __builtin_amdgcn_global_load_lds(
        (const __attribute__((address_space(1))) void*)g,
        (__attribute__((address_space(3))) void*)l, 16, 0, 0);
}

// ---------------- merged fp32 -> bf16 weight conversion (single launch) --------
__global__ __launch_bounds__(256) void cvt_all_kernel(
        const float* __restrict__ s0, const float* __restrict__ s1,
        const float* __restrict__ s2, const float* __restrict__ s3,
        const float* __restrict__ s4, const float* __restrict__ s5,
        short* __restrict__ dst) {
    const int b0 = 442368, b1 = 589824, b2 = 737280,
              b3 = 3096576, b4 = 3686400, b5 = 4276224;
    int i = blockIdx.x * 256 + threadIdx.x;
    if (i >= b5) return;
    const float* src; int off;
    if      (i < b0) { src = s0; off = i; }
    else if (i < b1) { src = s1; off = i - b0; }
    else if (i < b2) { src = s2; off = i - b1; }
    else if (i < b3) { src = s3; off = i - b2; }
    else if (i < b4) { src = s4; off = i - b3; }
    else             { src = s5; off = i - b4; }
    float4 v = ((const float4*)src)[off];
    ((short4*)dst)[i] = make_short4(f2bs(v.x), f2bs(v.y), f2bs(v.z), f2bs(v.w));
}

// ---------------- LN1 (fp32 in, bf16 out), vectorized x4 ----------------
__global__ __launch_bounds__(256) void ln1_kernel(const float* __restrict__ in,
        const float* __restrict__ g, const float* __restrict__ b,
        bf16* __restrict__ out, int Dg) {
    int row = blockIdx.x;
    int n4 = Dg >> 2;
    const float4* xr = (const float4*)(in + (size_t)row * Dg);
    float s = 0.f, s2 = 0.f;
    for (int c = threadIdx.x; c < n4; c += 256) {
        float4 v = xr[c];
        s += v.x + v.y + v.z + v.w;
        s2 += v.x * v.x + v.y * v.y + v.z * v.z + v.w * v.w;
    }
    __shared__ float r1[4], r2[4];
    for (int off = 32; off; off >>= 1) { s += __shfl_down(s, off, 64); s2 += __shfl_down(s2, off, 64); }
    if ((threadIdx.x & 63) == 0) { r1[threadIdx.x >> 6] = s; r2[threadIdx.x >> 6] = s2; }
    __syncthreads();
    s  = r1[0] + r1[1] + r1[2] + r1[3];
    s2 = r2[0] + r2[1] + r2[2] + r2[3];
    float mean = s / Dg;
    float rstd = rsqrtf(s2 / Dg - mean * mean + 1e-5f);
    short4* yr = (short4*)(out + (size_t)row * Dg);
    const float4* g4 = (const float4*)g;
    const float4* b4 = (const float4*)b;
    for (int c = threadIdx.x; c < n4; c += 256) {
        float4 v = xr[c], gg = g4[c], bb = b4[c];
        yr[c] = make_short4(f2bs((v.x - mean) * rstd * gg.x + bb.x),
                            f2bs((v.y - mean) * rstd * gg.y + bb.y),
                            f2bs((v.z - mean) * rstd * gg.z + bb.z),
                            f2bs((v.w - mean) * rstd * gg.w + bb.w));
    }
}

// ============== gemm256: 256x256 tile, BK=64, 8 waves, 8-phase schedule ========
// LDS: As/Bs[2 buf][256 rows][64 k] bf16 = 128 KiB. Tile t -> buf (t&1).
// Chunk-XOR swizzle identical to gemm_bf: LDS slot c of row r holds global
// k-chunk c^(r&7); reads use slot (ks*4+quad)^(r&7) -> 2-way bank aliasing only.
// Per-wave output 128x64 = acc[8][4]. Quadrant order (0,0),(0,1),(1,1),(1,0):
// set last-reads at distinct phases {A0:0, B1:1, A1:2, B0:3}, so each stage-set
// of tile T+2 is written exactly one phase after tile T's last read of it.
// Steady-state stage stream (rel. phases, iter computes T=2i buf0, T+1 buf1):
//   ph0: B0(T+1)  ph1: A0(T+2)  ph2: B1(T+2)  ph3: A1(T+2)
//   ph4: B0(T+2)  ph5: A0(T+3)  ph6: B1(T+3)  ph7: A1(T+3)
// vmcnt(6) = 2 loads/half x 3 halves-in-flight at end of ph3/ph7 guarantees the
// next tile's 4 halves landed (retired through B0) without ever draining to 0.
// Last iteration: stages for tiles >= ntiles skipped; ph3 uses vmcnt(0) to
// cover B0(T+1) staged at ph0 (needs Kc >= 384, i.e. niter >= 3: holds, K=768/3072).

#define G256_BAR        __builtin_amdgcn_s_barrier()
#define G256_LGKM0      asm volatile("s_waitcnt lgkmcnt(0)" ::: "memory")
#define G256_VM6        asm volatile("s_waitcnt vmcnt(6)" ::: "memory")
#define G256_VM0        asm volatile("s_waitcnt vmcnt(0)" ::: "memory")

// A stage-set SET (rows {SET*64..+63} u {128+SET*64..+63}), 2 x 16B per thread
#define G256_STAGE_A(BUF, SET, KT) do {                                        \
    _Pragma("unroll")                                                          \
    for (int qq = 0; qq < 2; ++qq) {                                           \
        int rl = qq * 128 + (SET) * 64 + (tid >> 3);                           \
        int rg = m0 + rl; if (rg > Mr - 1) rg = Mr - 1;                        \
        int jc = (tid & 7) ^ (rl & 7);                                         \
        gl_lds16(A + (size_t)rg * Kc + (KT) + jc * 8,                          \
                 As[BUF] + rl * 64 + (tid & 7) * 8);                           \
    } } while (0)

// B stage-set SET (rows with bit5==SET: 4 blocks of 32), 2 x 16B per thread
#define G256_STAGE_B(BUF, SET, KT) do {                                        \
    _Pragma("unroll")                                                          \
    for (int qq = 0; qq < 2; ++qq) {                                           \
        int rl = (qq * 2 + (tid >> 8)) * 64 + (SET) * 32 + ((tid & 255) >> 3); \
        int jc = (tid & 7) ^ (rl & 7);                                         \
        gl_lds16(W + (size_t)(n0 + rl) * Kc + (KT) + jc * 8,                   \
                 Bs[BUF] + rl * 64 + (tid & 7) * 8);                           \
    } } while (0)

#define G256_LDA(BUF, MQ) do {                                                 \
    _Pragma("unroll")                                                          \
    for (int i = 0; i < 4; ++i) {                                              \
        int row = wm * 128 + (MQ) * 64 + i * 16 + l16;                         \
        const short* rp = As[BUF] + row * 64;                                  \
        _Pragma("unroll")                                                      \
        for (int ks = 0; ks < 2; ++ks)                                         \
            a[i][ks] = *(const bf16x8*)(rp + (((ks * 4 + quad) ^ (row & 7)) << 3)); \
    } } while (0)

#define G256_LDB(BUF, NQ) do {                                                 \
    _Pragma("unroll")                                                          \
    for (int j = 0; j < 2; ++j) {                                              \
        int row = wn * 64 + (NQ) * 32 + j * 16 + l16;                          \
        const short* rp = Bs[BUF] + row * 64;                                  \
        _Pragma("unroll")                                                      \
        for (int ks = 0; ks < 2; ++ks)                                         \
            b[j][ks] = *(const bf16x8*)(rp + (((ks * 4 + quad) ^ (row & 7)) << 3)); \
    } } while (0)

#define G256_MMA(MQ, NQ) do {                                                  \
    __builtin_amdgcn_s_setprio(1);                                             \
    _Pragma("unroll")                                                          \
    for (int i = 0; i < 4; ++i)                                                \
        _Pragma("unroll")                                                      \
        for (int j = 0; j < 2; ++j)                                            \
            _Pragma("unroll")                                                  \
            for (int ks = 0; ks < 2; ++ks)                                     \
                acc[(MQ) * 4 + i][(NQ) * 2 + j] =                              \
                    __builtin_amdgcn_mfma_f32_16x16x32_bf16(                   \
                        a[i][ks], b[j][ks], acc[(MQ) * 4 + i][(NQ) * 2 + j], 0, 0, 0); \
    __builtin_amdgcn_s_setprio(0);                                             \
} while (0)

template<int MODE, typename TC>
__global__ __launch_bounds__(512, 2) void gemm256(const short* __restrict__ A,
        const short* __restrict__ W, const float* __restrict__ bias,
        const bf16* __restrict__ resid, TC* __restrict__ C,
        int Mr, int Nc, int Kc, int ntn)
{
    __shared__ short As[2][256 * 64];   // 64 KB
    __shared__ short Bs[2][256 * 64];   // 64 KB
    const int tid  = threadIdx.x;
    const int lane = tid & 63, wave = tid >> 6;
    const int wm = wave >> 2, wn = wave & 3;           // 2 x 4 wave grid
    const int quad = lane >> 4, l16 = lane & 15;

    // bijective XCD-aware swizzle (m204)
    const int nwg = gridDim.x;
    const int qd = nwg >> 3, rm = nwg & 7;
    const int xcd = blockIdx.x & 7, lin = blockIdx.x >> 3;
    const int wg = (xcd < rm ? xcd * (qd + 1) : rm * (qd + 1) + (xcd - rm) * qd) + lin;
    const int m0 = (wg / ntn) * 256, n0 = (wg % ntn) * 256;

    f32x4 acc[8][4];
#pragma unroll
    for (int i = 0; i < 8; ++i)
#pragma unroll
        for (int j = 0; j < 4; ++j) acc[i][j] = (f32x4){0.f, 0.f, 0.f, 0.f};
    bf16x8 a[4][2], b[2][2];

    const int niter = Kc >> 7;   // K tiles of 128 per iteration (2 x BK=64)

    // prologue: tile0 fully + tile1 {A0,B1,A1}; wait tile0 (oldest 8 of 14)
    G256_STAGE_A(0, 0, 0);  G256_STAGE_B(0, 1, 0);
    G256_STAGE_A(0, 1, 0);  G256_STAGE_B(0, 0, 0);
    G256_STAGE_A(1, 0, 64); G256_STAGE_B(1, 1, 64); G256_STAGE_A(1, 1, 64);
    G256_VM6;
    G256_BAR;

    for (int it = 0; it < niter; ++it) {
        const int kT = it * 128;
        const bool pre = (it + 1 < niter);
        // ---- ph0: q(0,0) of tile T (buf0) ----
        G256_LDA(0, 0); G256_LDB(0, 0);
        G256_STAGE_B(1, 0, kT + 64);                 // B0(T+1), always valid
        G256_BAR; G256_LGKM0;
        G256_MMA(0, 0);
        G256_BAR;
        // ---- ph1: q(0,1) ----
        G256_LDB(0, 1);
        if (pre) G256_STAGE_A(0, 0, kT + 128);       // A0(T+2)
        G256_BAR; G256_LGKM0;
        G256_MMA(0, 1);
        G256_BAR;
        // ---- ph2: q(1,1) ----
        G256_LDA(0, 1);
        if (pre) G256_STAGE_B(0, 1, kT + 128);       // B1(T+2)
        G256_BAR; G256_LGKM0;
        G256_MMA(1, 1);
        G256_BAR;
        // ---- ph3: q(1,0); tile boundary wait ----
        G256_LDB(0, 0);
        if (pre) G256_STAGE_A(0, 1, kT + 128);       // A1(T+2)
        G256_BAR; G256_LGKM0;
        G256_MMA(1, 0);
        if (pre) { G256_VM6; } else { G256_VM0; }    // tile T+1 fully landed
        G256_BAR;
        // ---- ph4: q(0,0) of tile T+1 (buf1) ----
        G256_LDA(1, 0); G256_LDB(1, 0);
        if (pre) G256_STAGE_B(0, 0, kT + 128);       // B0(T+2)
        G256_BAR; G256_LGKM0;
        G256_MMA(0, 0);
        G256_BAR;
        // ---- ph5: q(0,1) ----
        G256_LDB(1, 1);
        if (pre) G256_STAGE_A(1, 0, kT + 192);       // A0(T+3)
        G256_BAR; G256_LGKM0;
        G256_MMA(0, 1);
        G256_BAR;
        // ---- ph6: q(1,1) ----
        G256_LDA(1, 1);
        if (pre) G256_STAGE_B(1, 1, kT + 192);       // B1(T+3)
        G256_BAR; G256_LGKM0;
        G256_MMA(1, 1);
        G256_BAR;
        // ---- ph7: q(1,0); tile boundary wait ----
        G256_LDB(1, 0);
        if (pre) G256_STAGE_A(1, 1, kT + 192);       // A1(T+3)
        G256_BAR; G256_LGKM0;
        G256_MMA(1, 0);
        G256_VM6;                                    // tile T+2 landed (no-op at end)
        G256_BAR;
    }

    // Epilogue. C/D layout: col = lane&15, row = quad*4 + reg  [m89/m91 verified]
#pragma unroll
    for (int fm = 0; fm < 8; ++fm)
#pragma unroll
        for (int r = 0; r < 4; ++r) {
            int row = m0 + wm * 128 + fm * 16 + quad * 4 + r;
            if (row >= Mr) continue;
#pragma unroll
            for (int fn = 0; fn < 4; ++fn) {
                int col = n0 + wn * 64 + fn * 16 + l16;
                float v = acc[fm][fn][r] + bias[col];
                if (MODE == 1) v = gelu_exact(v);
                if (MODE == 2) v += b2f(resid[(size_t)row * Nc + col]);
                st1(C + (size_t)row * Nc + col, v);
            }
        }
}

// ---------------- MFMA GEMM (bf16 x bf16): BK=64, XOR-swizzled LDS --------------
// (kept for small-N GEMMs: proj/wa/f2 — 594-block grids pack CUs better)
template<int MODE, typename TC>
__global__ __launch_bounds__(256) void gemm_bf(const short* __restrict__ A,
        const short* __restrict__ W, const float* __restrict__ bias,
        const bf16* __restrict__ resid, TC* __restrict__ C,
        int Mr, int Nc, int Kc)
{
    __shared__ short Abuf[128 * 64];   // 16 KB
    __shared__ short Bbuf[128 * 64];   // 16 KB
    const int tid  = threadIdx.x;
    const int lane = tid & 63, wave = tid >> 6;
    const int wm = wave & 1, wn = wave >> 1;
    const int quad = lane >> 4, l16 = lane & 15;
    const int m0 = blockIdx.y * 128, n0 = blockIdx.x * 128;

    f32x4 acc[4][4];
#pragma unroll
    for (int i = 0; i < 4; ++i)
#pragma unroll
        for (int j = 0; j < 4; ++j) acc[i][j] = (f32x4){0.f, 0.f, 0.f, 0.f};

    for (int k0 = 0; k0 < Kc; k0 += 64) {
        __syncthreads();   // prior slab's ds_reads done before LDS overwrite
#pragma unroll
        for (int q = 0; q < 4; ++q) {
            int c = q * 256 + tid;
            int row = c >> 3;
            int j = (c & 7) ^ (row & 7);      // global k-chunk for this LDS slot
            int rowA = m0 + row;
            if (rowA > Mr - 1) rowA = Mr - 1; // clamp tail tile (discarded at store)
            gl_lds16(A + (size_t)rowA * Kc + k0 + j * 8, Abuf + c * 8);
        }
#pragma unroll
        for (int q = 0; q < 4; ++q) {
            int c = q * 256 + tid;
            int row = c >> 3;
            int j = (c & 7) ^ (row & 7);
            gl_lds16(W + (size_t)(n0 + row) * Kc + k0 + j * 8, Bbuf + c * 8);
        }
        __syncthreads();   // drains vmcnt (global_load_lds)
#pragma unroll
        for (int t = 0; t < 2; ++t) {
            bf16x8 fa[4], fb[4];
#pragma unroll
            for (int i = 0; i < 4; ++i) {
                int r = wm * 64 + i * 16 + l16;
                fa[i] = *(const bf16x8*)(Abuf + r * 64 + (((t * 4 + quad) ^ (r & 7)) << 3));
            }
#pragma unroll
            for (int j = 0; j < 4; ++j) {
                int r = wn * 64 + j * 16 + l16;
                fb[j] = *(const bf16x8*)(Bbuf + r * 64 + (((t * 4 + quad) ^ (r & 7)) << 3));
            }
#pragma unroll
            for (int i = 0; i < 4; ++i)
#pragma unroll
                for (int j = 0; j < 4; ++j)
                    acc[i][j] = __builtin_amdgcn_mfma_f32_16x16x32_bf16(fa[i], fb[j], acc[i][j], 0, 0, 0);
        }
    }

    // Epilogue. C/D layout: col = lane&15, row = quad*4 + reg  [m89/m91 verified]
#pragma unroll
    for (int i = 0; i < 4; ++i)
#pragma unroll
        for (int r = 0; r < 4; ++r) {
            int row = m0 + wm * 64 + i * 16 + quad * 4 + r;
            if (row >= Mr) continue;
#pragma unroll
            for (int j = 0; j < 4; ++j) {
                int col = n0 + wn * 64 + j * 16 + l16;
                float v = acc[i][j][r] + bias[col];
                if (MODE == 1) v = gelu_exact(v);
                if (MODE == 2) v += b2f(resid[(size_t)row * Nc + col]);
                st1(C + (size_t)row * Nc + col, v);
            }
        }
}

// ---------------- fallback GEMM (fp32 weights, BK=32, round-6 proven) -----------
template<int MODE, typename TC>
__global__ __launch_bounds__(256) void gemm_f32b(const short* __restrict__ A,
        const float* __restrict__ W, const float* __restrict__ bias,
        const bf16* __restrict__ resid, TC* __restrict__ C,
        int Mr, int Nc, int Kc)
{
    __shared__ short Abuf[128 * 32];
    __shared__ short Bbuf[128 * 32];
    const int tid  = threadIdx.x;
    const int lane = tid & 63, wave = tid >> 6;
    const int wm = wave & 1, wn = wave >> 1;
    const int quad = lane >> 4, l16 = lane & 15;
    const int m0 = blockIdx.y * 128, n0 = blockIdx.x * 128;
    f32x4 acc[4][4];
#pragma unroll
    for (int i = 0; i < 4; ++i)
#pragma unroll
        for (int j = 0; j < 4; ++j) acc[i][j] = (f32x4){0.f, 0.f, 0.f, 0.f};
    const int brow = tid >> 3;
    const int bk   = (tid & 7) * 4;
    for (int k0 = 0; k0 < Kc; k0 += 32) {
        float4 wv[4];
#pragma unroll
        for (int s = 0; s < 4; ++s)
            wv[s] = *(const float4*)(W + (size_t)(n0 + s * 32 + brow) * Kc + k0 + bk);
        __syncthreads();
#pragma unroll
        for (int q = 0; q < 2; ++q) {
            int c = q * 256 + tid;
            int rowA = m0 + (c >> 2);
            if (rowA > Mr - 1) rowA = Mr - 1;
            gl_lds16(A + (size_t)rowA * Kc + k0 + (c & 3) * 8, Abuf + c * 8);
        }
#pragma unroll
        for (int s = 0; s < 4; ++s) {
            short4 h = make_short4(f2bs(wv[s].x), f2bs(wv[s].y), f2bs(wv[s].z), f2bs(wv[s].w));
            *(short4*)(Bbuf + (s * 32 + brow) * 32 + bk) = h;
        }
        __syncthreads();
        bf16x8 fa[4], fb[4];
#pragma unroll
        for (int i = 0; i < 4; ++i)
            fa[i] = *(const bf16x8*)(Abuf + (wm * 64 + i * 16 + l16) * 32 + quad * 8);
#pragma unroll
        for (int j = 0; j < 4; ++j)
            fb[j] = *(const bf16x8*)(Bbuf + (wn * 64 + j * 16 + l16) * 32 + quad * 8);
#pragma unroll
        for (int i = 0; i < 4; ++i)
#pragma unroll
            for (int j = 0; j < 4; ++j)
                acc[i][j] = __builtin_amdgcn_mfma_f32_16x16x32_bf16(fa[i], fb[j], acc[i][j], 0, 0, 0);
    }
#pragma unroll
    for (int i = 0; i < 4; ++i)
#pragma unroll
        for (int r = 0; r < 4; ++r) {
            int row = m0 + wm * 64 + i * 16 + quad * 4 + r;
            if (row >= Mr) continue;
#pragma unroll
            for (int j = 0; j < 4; ++j) {
                int col = n0 + wn * 64 + j * 16 + l16;
                float v = acc[i][j][r] + bias[col];
                if (MODE == 1) v = gelu_exact(v);
                if (MODE == 2) v += b2f(resid[(size_t)row * Nc + col]);
                st1(C + (size_t)row * Nc + col, v);
            }
        }
}

// ---------------- Attention (MFMA): one block per (b,h) ----------------
__global__ __launch_bounds__(256) void attn_mfma(const bf16* __restrict__ qkv,
        bf16* __restrict__ ctx) {
    const int NS = 197;
    const int KST = 104;
    const int VST = 232;
    __shared__ short Kbuf[224 * KST];
    __shared__ short Vt[96 * VST];
    __shared__ short Pbuf[4][16 * VST];
    const int b = blockIdx.x >> 3, h = blockIdx.x & 7;
    const short* base = (const short*)qkv + (size_t)b * NS * 2304 + h * 96;
    const int tid = threadIdx.x;

    for (int c = tid; c < NS * 12; c += 256) {
        int key = c / 12, dc = c % 12;
        bf16x8 v = *(const bf16x8*)(base + (size_t)key * 2304 + 768 + dc * 8);
        *(bf16x8*)(Kbuf + key * KST + dc * 8) = v;
    }
    for (int c = tid; c < 27 * 12; c += 256) {
        int key = NS + c / 12, dc = c % 12;
        *(bf16x8*)(Kbuf + key * KST + dc * 8) = (bf16x8){0, 0, 0, 0, 0, 0, 0, 0};
    }
    for (int c = tid; c < NS * 12; c += 256) {
        int key = c / 12, dc = c % 12;
        bf16x8 v = *(const bf16x8*)(base + (size_t)key * 2304 + 1536 + dc * 8);
#pragma unroll
        for (int j = 0; j < 8; ++j) Vt[(dc * 8 + j) * VST + key] = v[j];
    }
    for (int c = tid; c < 96 * 27; c += 256) {
        int d = c / 27, key = NS + c % 27;
        Vt[d * VST + key] = 0;
    }
    __syncthreads();

    const int wave = tid >> 6, lane = tid & 63;
    const int quad = lane >> 4, l16 = lane & 15;
    short* P = &Pbuf[wave][0];

    for (int qt = wave; qt < 13; qt += 4) {
        int qrow = qt * 16 + l16; if (qrow > NS - 1) qrow = NS - 1;
        bf16x8 fq[3];
#pragma unroll
        for (int kc = 0; kc < 3; ++kc)
            fq[kc] = *(const bf16x8*)(base + (size_t)qrow * 2304 + kc * 32 + quad * 8);
        f32x4 s[14];
#pragma unroll
        for (int nt = 0; nt < 14; ++nt) {
            s[nt] = (f32x4){0.f, 0.f, 0.f, 0.f};
#pragma unroll
            for (int kc = 0; kc < 3; ++kc) {
                bf16x8 fk = *(const bf16x8*)(Kbuf + (nt * 16 + l16) * KST + kc * 32 + quad * 8);
                s[nt] = __builtin_amdgcn_mfma_f32_16x16x32_bf16(fq[kc], fk, s[nt], 0, 0, 0);
            }
        }
        const float sc = 0.10206207261596577f;
        float mx[4] = {-1e30f, -1e30f, -1e30f, -1e30f};
#pragma unroll
        for (int nt = 0; nt < 14; ++nt) {
            bool valid = nt * 16 + l16 < NS;
#pragma unroll
            for (int r = 0; r < 4; ++r) {
                float v = s[nt][r] * sc;
                s[nt][r] = v;
                if (valid) mx[r] = fmaxf(mx[r], v);
            }
        }
#pragma unroll
        for (int m = 1; m < 16; m <<= 1)
#pragma unroll
            for (int r = 0; r < 4; ++r) mx[r] = fmaxf(mx[r], __shfl_xor(mx[r], m, 64));
        float l[4] = {0.f, 0.f, 0.f, 0.f};
#pragma unroll
        for (int nt = 0; nt < 14; ++nt) {
            bool valid = nt * 16 + l16 < NS;
#pragma unroll
            for (int r = 0; r < 4; ++r) {
                float e = valid ? __expf(s[nt][r] - mx[r]) : 0.f;
                l[r] += e;
                P[(quad * 4 + r) * VST + nt * 16 + l16] = f2bs(e);
            }
        }
#pragma unroll
        for (int m = 1; m < 16; m <<= 1)
#pragma unroll
            for (int r = 0; r < 4; ++r) l[r] += __shfl_xor(l[r], m, 64);
        __asm__ volatile("s_waitcnt lgkmcnt(0)" ::: "memory");
        f32x4 o[6];
#pragma unroll
        for (int nt = 0; nt < 6; ++nt) o[nt] = (f32x4){0.f, 0.f, 0.f, 0.f};
#pragma unroll
        for (int kc = 0; kc < 7; ++kc) {
            bf16x8 fp = *(const bf16x8*)(P + l16 * VST + kc * 32 + quad * 8);
#pragma unroll
            for (int nt = 0; nt < 6; ++nt) {
                bf16x8 fv = *(const bf16x8*)(Vt + (nt * 16 + l16) * VST + kc * 32 + quad * 8);
                o[nt] = __builtin_amdgcn_mfma_f32_16x16x32_bf16(fp, fv, o[nt], 0, 0, 0);
            }
        }
        float inv[4];
#pragma unroll
        for (int r = 0; r < 4; ++r) inv[r] = 1.f / l[r];
#pragma unroll
        for (int r = 0; r < 4; ++r) {
            int q = qt * 16 + quad * 4 + r;
            if (q >= NS) continue;
            bf16* orow = ctx + ((size_t)(b * NS + q)) * 768 + h * 96;
#pragma unroll
            for (int nt = 0; nt < 6; ++nt)
                orow[nt * 16 + l16] = __float2bfloat16(o[nt][r] * inv[r]);
        }
    }
}

// ---------------- SO(8) adapter tail: rotate + err + LN + residuals -------------
template<bool OUTER, bool FINAL, bool FLN2>
__global__ __launch_bounds__(256) void adapter_finish(
        const bf16* __restrict__ xp, const bf16* __restrict__ xin,
        const float* __restrict__ xouter, const float* __restrict__ eps,
        const float* __restrict__ scale_p, const float* __restrict__ g,
        const float* __restrict__ bta, bf16* __restrict__ out,
        float* __restrict__ e_acc, float* __restrict__ e_out,
        const float* __restrict__ g2, const float* __restrict__ b2,
        bf16* __restrict__ out2, int Dg)
{
    extern __shared__ float smem[];
    float* y = smem;            // Dg
    float* diff2 = smem + Dg;   // 64
    float* red = diff2 + 64;    // 8 head-norms
    float* r1 = red + 8;        // 4
    float* r2 = red + 12;       // 4
    int row = blockIdx.x;
    int hd = Dg >> 3;           // 96 or 384
    int hd8 = hd >> 3;          // chunks per head
    int n8 = Dg >> 3;
    const bf16* xpr = xp + (size_t)row * Dg;
    const bf16* xir = xin + (size_t)row * Dg;
    int tid = threadIdx.x;
    if (tid < 64) {
        int hh = tid >> 3, i = tid & 7, p = i >> 1;
        float ang = eps[((size_t)row * 8 + hh) * 4 + p] * scale_p[0];
        float c = cosf(ang), sn = sinf(ang);
        int base = hh * hd;
        float ev = b2f(xpr[base + 2 * p]), od = b2f(xpr[base + 2 * p + 1]);
        float r = (i & 1) ? (ev * sn + od * c) : (ev * c - od * sn);
        float d = r - b2f(xpr[base + i]);
        diff2[tid] = d * d;
        y[base + i] = r + b2f(xir[base + i]);
    }
    for (int c8 = tid; c8 < n8; c8 += 256) {
        if (c8 % hd8 == 0) continue;   // rot chunk: handled above
        float a[8], bvx[8];
        b8f(*(const bf16x8*)(xpr + c8 * 8), a);
        b8f(*(const bf16x8*)(xir + c8 * 8), bvx);
#pragma unroll
        for (int j = 0; j < 8; ++j) y[c8 * 8 + j] = a[j] + bvx[j];
    }
    __syncthreads();
    if (tid < 8) {
        float t = 0.f;
#pragma unroll
        for (int i = 0; i < 8; ++i) t += diff2[tid * 8 + i];
        red[tid] = sqrtf(t);
    }
    float s = 0.f, s2 = 0.f;
    for (int c = tid; c < Dg; c += 256) { float v = y[c]; s += v; s2 += v * v; }
    for (int off = 32; off; off >>= 1) { s += __shfl_down(s, off, 64); s2 += __shfl_down(s2, off, 64); }
    if ((tid & 63) == 0) { r1[tid >> 6] = s; r2[tid >> 6] = s2; }
    __syncthreads();
    s  = r1[0] + r1[1] + r1[2] + r1[3];
    s2 = r2[0] + r2[1] + r2[2] + r2[3];
    float mean = s / Dg;
    float rstd = rsqrtf(s2 / Dg - mean * mean + 1e-5f);
    if (tid == 0) {
        float e = (red[0] + red[1] + red[2] + red[3] + red[4] + red[5] + red[6] + red[7]) * 0.125f;
        if (FINAL) e_out[row] = e_acc[row] + e;
        else       e_acc[row] = e;
    }
    bf16* outr = out + (size_t)row * Dg;
    const float4* g4 = (const float4*)g;
    const float4* bt4 = (const float4*)bta;
    const float4* xo4 = OUTER ? (const float4*)(xouter + (size_t)row * Dg) : nullptr;
    float sB = 0.f, sB2 = 0.f;
    for (int c8 = tid; c8 < n8; c8 += 256) {
        float xi[8];
        b8f(*(const bf16x8*)(xir + c8 * 8), xi);
        float4 gg0 = g4[c8 * 2], gg1 = g4[c8 * 2 + 1];
        float4 bb0 = bt4[c8 * 2], bb1 = bt4[c8 * 2 + 1];
        float gv[8] = {gg0.x, gg0.y, gg0.z, gg0.w, gg1.x, gg1.y, gg1.z, gg1.w};
        float bv[8] = {bb0.x, bb0.y, bb0.z, bb0.w, bb1.x, bb1.y, bb1.z, bb1.w};
        float vv[8];
#pragma unroll
        for (int j = 0; j < 8; ++j)
            vv[j] = (y[c8 * 8 + j] - mean) * rstd * gv[j] + bv[j] + xi[j];
        if (OUTER) {
            float4 o0 = xo4[c8 * 2], o1 = xo4[c8 * 2 + 1];
            float ov[8] = {o0.x, o0.y, o0.z, o0.w, o1.x, o1.y, o1.z, o1.w};
#pragma unroll
            for (int j = 0; j < 8; ++j) vv[j] += ov[j];
        }
        *(bf16x8*)(outr + c8 * 8) = f8b(vv);
        if (FLN2) {
#pragma unroll
            for (int j = 0; j < 8; ++j) {
                y[c8 * 8 + j] = vv[j];
                sB += vv[j]; sB2 += vv[j] * vv[j];
            }
        }
    }
    if (FLN2) {
        __syncthreads();   // all reads of r1/r2 and y done
        for (int off = 32; off; off >>= 1) { sB += __shfl_down(sB, off, 64); sB2 += __shfl_down(sB2, off, 64); }
        if ((tid & 63) == 0) { r1[tid >> 6] = sB; r2[tid >> 6] = sB2; }
        __syncthreads();
        sB  = r1[0] + r1[1] + r1[2] + r1[3];
        sB2 = r2[0] + r2[1] + r2[2] + r2[3];
        float mean2 = sB / Dg;
        float rstd2 = rsqrtf(sB2 / Dg - mean2 * mean2 + 1e-5f);
        bf16* o2r = out2 + (size_t)row * Dg;
        const float4* g24 = (const float4*)g2;
        const float4* b24 = (const float4*)b2;
        for (int c8 = tid; c8 < n8; c8 += 256) {
            float4 gg0 = g24[c8 * 2], gg1 = g24[c8 * 2 + 1];
            float4 bb0 = b24[c8 * 2], bb1 = b24[c8 * 2 + 1];
            float gv[8] = {gg0.x, gg0.y, gg0.z, gg0.w, gg1.x, gg1.y, gg1.z, gg1.w};
            float bv[8] = {bb0.x, bb0.y, bb0.z, bb0.w, bb1.x, bb1.y, bb1.z, bb1.w};
            float vv[8];
#pragma unroll
            for (int j = 0; j < 8; ++j)
                vv[j] = (y[c8 * 8 + j] - mean2) * rstd2 * gv[j] + bv[j];
            *(bf16x8*)(o2r + c8 * 8) = f8b(vv);
        }
    }
}

extern "C" void kernel_launch(void* const* d_in, const int* in_sizes, int n_in,
                              void* d_out, int out_size, void* d_ws, size_t ws_size,
                              hipStream_t stream) {
    (void)in_sizes; (void)n_in; (void)out_size;
    const int M = MROWS;
    const size_t S_D = (size_t)M * DMODEL;
    const size_t S_H = (size_t)M * DHID;

    const float* x      = (const float*)d_in[0];
    const float* qkv_w  = (const float*)d_in[1];
    const float* qkv_b  = (const float*)d_in[2];
    const float* proj_w = (const float*)d_in[3];
    const float* proj_b = (const float*)d_in[4];
    const float* n1g    = (const float*)d_in[5];
    const float* n1b    = (const float*)d_in[6];
    const float* n2g    = (const float*)d_in[7];
    const float* n2b    = (const float*)d_in[8];
    const float* wa     = (const float*)d_in[9];
    const float* ba     = (const float*)d_in[10];
    const float* sca    = (const float*)d_in[11];
    const float* lga    = (const float*)d_in[12];
    const float* lba    = (const float*)d_in[13];
    const float* wm     = (const float*)d_in[14];
    const float* bm     = (const float*)d_in[15];
    const float* scm    = (const float*)d_in[16];
    const float* lgm    = (const float*)d_in[17];
    const float* lbm    = (const float*)d_in[18];
    const float* f1w    = (const float*)d_in[19];
    const float* f1b    = (const float*)d_in[20];
    const float* f2w    = (const float*)d_in[21];
    const float* f2b    = (const float*)d_in[22];
    const float* eps_a  = (const float*)d_in[23];
    const float* eps_m  = (const float*)d_in[24];

    float* out_x = (float*)d_out;          // M*768 fp32
    float* out_e = out_x + S_D;            // M fp32 (e1+e2)

    bf16* R1 = (bf16*)d_ws;
    bf16* R2 = R1 + S_H;
    bf16* R3 = R2 + S_H;
    float* E = (float*)(R3 + S_D);

    const size_t n_qkv = (size_t)2304 * 768, n_proj = (size_t)768 * 768,
                 n_wa = (size_t)768 * 768, n_wm = (size_t)3072 * 3072,
                 n_f1 = (size_t)3072 * 768, n_f2 = (size_t)768 * 3072;
    const size_t base_bytes = (2 * S_H + S_D) * 2 + (size_t)M * 4;
    const size_t w_elems = n_qkv + n_proj + n_wa + n_wm + n_f1 + n_f2;
    const bool cache_w = ws_size >= base_bytes + w_elems * 2;

    short* WB    = (short*)((char*)d_ws + base_bytes);
    short* wb_qkv = WB;
    short* wb_proj = wb_qkv + n_qkv;
    short* wb_wa  = wb_proj + n_proj;
    short* wb_wm  = wb_wa + n_wa;
    short* wb_f1  = wb_wm + n_wm;
    short* wb_f2  = wb_f1 + n_f1;

    const int GY = (M + 127) / 128;     // 99
    const int GY256 = (M + 255) / 256;  // 50
    const size_t lds_a = (DMODEL + 96) * sizeof(float);
    const size_t lds_m = (DHID + 96) * sizeof(float);

    if (cache_w) {
        cvt_all_kernel<<<(4276224 + 255) / 256, 256, 0, stream>>>(
            qkv_w, proj_w, wa, wm, f1w, f2w, WB);
        ln1_kernel<<<M, 256, 0, stream>>>(x, n1g, n1b, R1, DMODEL);
        gemm256<0, bf16><<<dim3((2304 / 256) * GY256), 512, 0, stream>>>(
            (const short*)R1, wb_qkv, qkv_b, nullptr, R2, M, 2304, DMODEL, 2304 / 256);
        attn_mfma<<<64 * 8, 256, 0, stream>>>(R2, R1);
        gemm_bf<0, bf16><<<dim3(DMODEL / 128, GY), 256, 0, stream>>>(
            (const short*)R1, wb_proj, proj_b, nullptr, R2, M, DMODEL, DMODEL);
        gemm_bf<0, bf16><<<dim3(DMODEL / 128, GY), 256, 0, stream>>>(
            (const short*)R2, wb_wa, ba, nullptr, R1, M, DMODEL, DMODEL);
        // adapter-A + fused LN2: x_new -> R3, LN2(x_new) -> R2, e1 -> E
        adapter_finish<true, false, true><<<M, 256, lds_a, stream>>>(
            R1, R2, x, eps_a, sca, lga, lba, R3, E, nullptr, n2g, n2b, R2, DMODEL);
        gemm256<1, bf16><<<dim3((DHID / 256) * GY256), 512, 0, stream>>>(
            (const short*)R2, wb_f1, f1b, nullptr, R1, M, DHID, DMODEL, DHID / 256);
        gemm256<0, bf16><<<dim3((DHID / 256) * GY256), 512, 0, stream>>>(
            (const short*)R1, wb_wm, bm, nullptr, R2, M, DHID, DHID, DHID / 256);
        adapter_finish<false, true, false><<<M, 256, lds_m, stream>>>(
            R2, R1, nullptr, eps_m, scm, lgm, lbm, R1, E, out_e, nullptr, nullptr, nullptr, DHID);
        gemm_bf<2, float><<<dim3(DMODEL / 128, GY), 256, 0, stream>>>(
            (const short*)R1, wb_f2, f2b, R3, out_x, M, DMODEL, DHID);
    } else {
        ln1_kernel<<<M, 256, 0, stream>>>(x, n1g, n1b, R1, DMODEL);
        gemm_f32b<0, bf16><<<dim3(2304 / 128, GY), 256, 0, stream>>>(
            (const short*)R1, qkv_w, qkv_b, nullptr, R2, M, 2304, DMODEL);
        attn_mfma<<<64 * 8, 256, 0, stream>>>(R2, R1);
        gemm_f32b<0, bf16><<<dim3(DMODEL / 128, GY), 256, 0, stream>>>(
            (const short*)R1, proj_w, proj_b, nullptr, R2, M, DMODEL, DMODEL);
        gemm_f32b<0, bf16><<<dim3(DMODEL / 128, GY), 256, 0, stream>>>(
            (const short*)R2, wa, ba, nullptr, R1, M, DMODEL, DMODEL);
        adapter_finish<true, false, true><<<M, 256, lds_a, stream>>>(
            R1, R2, x, eps_a, sca, lga, lba, R3, E, nullptr, n2g, n2b, R2, DMODEL);
        gemm_f32b<1, bf16><<<dim3(DHID / 128, GY), 256, 0, stream>>>(
            (const short*)R2, f1w, f1b, nullptr, R1, M, DHID, DMODEL);
        gemm_f32b<0, bf16><<<dim3(DHID / 128, GY), 256, 0, stream>>>(
            (const short*)R1, wm, bm, nullptr, R2, M, DHID, DHID);
        adapter_finish<false, true, false><<<M, 256, lds_m, stream>>>(
            R2, R1, nullptr, eps_m, scm, lgm, lbm, R1, E, out_e, nullptr, nullptr, nullptr, DHID);
        gemm_f32b<2, float><<<dim3(DMODEL / 128, GY), 256, 0, stream>>>(
            (const short*)R1, f2w, f2b, R3, out_x, M, DMODEL, DHID);
    }
}

// Round 2
// 899.166 us; speedup vs baseline: 1.0884x; 1.0884x over previous
//
#include <hip/hip_runtime.h>
#include <hip/hip_bf16.h>
#include <math.h>

// Problem constants (B=64, N=197, D=768, NH=8, HID=3072).
// fp32 global I/O; bf16 ws intermediates; bf16 weight cache in ws when it fits.
// wm GEMM (3072x3072): gemm256 v2 — 256x256 tile, BK=64, 8 waves, 8 phases with
// ONE barrier per phase (wave-skew overlaps LDS service + stage issue with
// straggler MFMA), stage-delay-2 schedule, counted vmcnt(4) at ph3/ph7.
// qkv/fc1/proj/wa/f2: proven 128x128 2-barrier kernel (3 blocks/CU implicit
// overlap, m114).
#define MROWS (64*197)   // 12608 rows
#define DMODEL 768
#define DHID   3072

typedef __hip_bfloat16 bf16;
using bf16x8 = __attribute__((ext_vector_type(8))) short;  // 8 bf16 (4 VGPRs)
using f32x4  = __attribute__((ext_vector_type(4))) float;  // MFMA accumulator

__device__ __forceinline__ float b2f(bf16 v) { return __bfloat162float(v); }
__device__ __forceinline__ short f2bs(float f) {
    bf16 h = __float2bfloat16(f);
    return *reinterpret_cast<short*>(&h);
}
__device__ __forceinline__ void b8f(bf16x8 v, float* f) {
#pragma unroll
    for (int j = 0; j < 8; ++j)
        f[j] = __uint_as_float(((unsigned int)(unsigned short)v[j]) << 16);
}
__device__ __forceinline__ bf16x8 f8b(const float* f) {
    bf16x8 r;
#pragma unroll
    for (int j = 0; j < 8; ++j) r[j] = f2bs(f[j]);
    return r;
}
__device__ __forceinline__ float gelu_exact(float v) {
    return 0.5f * v * (1.0f + erff(v * 0.70710678118654752f));
}
__device__ __forceinline__ void st1(bf16* p, float v) { *p = __float2bfloat16(v); }
__device__ __forceinline__ void st1(float* p, float v) { *p = v; }

// async global(16B) -> LDS, gfx950 width-16 variant
__device__ __forceinline__ void gl_lds16(const short* g, short* l) {
    __builtin_amdgcn_global_load_lds(
        (const __attribute__((address_space(1))) void*)g,
        (__attribute__((address_space(3))) void*)l, 16, 0, 0);
}

// ---------------- merged fp32 -> bf16 weight conversion (single launch) --------
__global__ __launch_bounds__(256) void cvt_all_kernel(
        const float* __restrict__ s0, const float* __restrict__ s1,
        const float* __restrict__ s2, const float* __restrict__ s3,
        const float* __restrict__ s4, const float* __restrict__ s5,
        short* __restrict__ dst) {
    const int b0 = 442368, b1 = 589824, b2 = 737280,
              b3 = 3096576, b4 = 3686400, b5 = 4276224;
    int i = blockIdx.x * 256 + threadIdx.x;
    if (i >= b5) return;
    const float* src; int off;
    if      (i < b0) { src = s0; off = i; }
    else if (i < b1) { src = s1; off = i - b0; }
    else if (i < b2) { src = s2; off = i - b1; }
    else if (i < b3) { src = s3; off = i - b2; }
    else if (i < b4) { src = s4; off = i - b3; }
    else             { src = s5; off = i - b4; }
    float4 v = ((const float4*)src)[off];
    ((short4*)dst)[i] = make_short4(f2bs(v.x), f2bs(v.y), f2bs(v.z), f2bs(v.w));
}

// ---------------- LN1 (fp32 in, bf16 out), vectorized x4 ----------------
__global__ __launch_bounds__(256) void ln1_kernel(const float* __restrict__ in,
        const float* __restrict__ g, const float* __restrict__ b,
        bf16* __restrict__ out, int Dg) {
    int row = blockIdx.x;
    int n4 = Dg >> 2;
    const float4* xr = (const float4*)(in + (size_t)row * Dg);
    float s = 0.f, s2 = 0.f;
    for (int c = threadIdx.x; c < n4; c += 256) {
        float4 v = xr[c];
        s += v.x + v.y + v.z + v.w;
        s2 += v.x * v.x + v.y * v.y + v.z * v.z + v.w * v.w;
    }
    __shared__ float r1[4], r2[4];
    for (int off = 32; off; off >>= 1) { s += __shfl_down(s, off, 64); s2 += __shfl_down(s2, off, 64); }
    if ((threadIdx.x & 63) == 0) { r1[threadIdx.x >> 6] = s; r2[threadIdx.x >> 6] = s2; }
    __syncthreads();
    s  = r1[0] + r1[1] + r1[2] + r1[3];
    s2 = r2[0] + r2[1] + r2[2] + r2[3];
    float mean = s / Dg;
    float rstd = rsqrtf(s2 / Dg - mean * mean + 1e-5f);
    short4* yr = (short4*)(out + (size_t)row * Dg);
    const float4* g4 = (const float4*)g;
    const float4* b4 = (const float4*)b;
    for (int c = threadIdx.x; c < n4; c += 256) {
        float4 v = xr[c], gg = g4[c], bb = b4[c];
        yr[c] = make_short4(f2bs((v.x - mean) * rstd * gg.x + bb.x),
                            f2bs((v.y - mean) * rstd * gg.y + bb.y),
                            f2bs((v.z - mean) * rstd * gg.z + bb.z),
                            f2bs((v.w - mean) * rstd * gg.w + bb.w));
    }
}

// ============== gemm256 v2: 256x256 tile, BK=64, 8 waves, single-bar phases ====
// LDS: As/Bs[2 buf][256 rows][64 k] bf16 = 128 KiB. Tile t -> buf (t&1).
// Chunk-XOR swizzle: LDS slot c of row r holds global k-chunk c^(r&7).
// ONE barrier per phase: [reads; stage; (vmcnt); bar; lgkm0; MFMA]. A fast wave
// proceeds to the next phase's reads/stage while stragglers MFMA -> LDS service
// and load issue overlap MFMA via wave skew (1 block/CU has nothing else).
// Stage-safety rule: stage of set S >= 2 phases after last read of S
// (reader's lgkm0 in p-2 precedes bar_{p-1}, which the stager passes first).
// Quadrant order (0,0),(0,1),(1,1),(1,0); B0 re-read at ph3/ph7.
// Last reads: A0:ph0 B1:ph1 A1:ph2 B0:ph3 (buf0); +4 for buf1.
// Stage schedule (iter computes T=2it buf0 @ph0-3, T+1 buf1 @ph4-7):
//   ph0: A1b1(T+1)  ph1: B0b1(T+1)  ph2: A0b0(T+2)  ph3: B1b0(T+2) +vmcnt(4)
//   ph4: A1b0(T+2)  ph5: B0b0(T+2)  ph6: A0b1(T+3)  ph7: B1b1(T+3) +vmcnt(4)
// vmcnt(4) (2 loads/stage, 6 stages outstanding = 12) drains the oldest 8 =
// exactly the 4 sets of the half-tile about to be read; placed BEFORE the
// barrier so cross-wave visibility is guaranteed by vmcnt->barrier ordering.
// Last iteration skips T+2/T+3 stages and uses vmcnt(0) at ph3/ph7.

#define G256_BAR        __builtin_amdgcn_s_barrier()
#define G256_LGKM0      asm volatile("s_waitcnt lgkmcnt(0)" ::: "memory")
#define G256_VM4        asm volatile("s_waitcnt vmcnt(4)" ::: "memory")
#define G256_VM0        asm volatile("s_waitcnt vmcnt(0)" ::: "memory")

// A stage-set SET (rows {SET*64..+63} u {128+SET*64..+63}), 2 x 16B per thread
#define G256_STAGE_A(BUF, SET, KT) do {                                        \
    _Pragma("unroll")                                                          \
    for (int qq = 0; qq < 2; ++qq) {                                           \
        int rl = qq * 128 + (SET) * 64 + (tid >> 3);                           \
        int rg = m0 + rl; if (rg > Mr - 1) rg = Mr - 1;                        \
        int jc = (tid & 7) ^ (rl & 7);                                         \
        gl_lds16(A + (size_t)rg * Kc + (KT) + jc * 8,                          \
                 As[BUF] + rl * 64 + (tid & 7) * 8);                           \
    } } while (0)

// B stage-set SET (rows with bit5==SET: 4 blocks of 32), 2 x 16B per thread
#define G256_STAGE_B(BUF, SET, KT) do {                                        \
    _Pragma("unroll")                                                          \
    for (int qq = 0; qq < 2; ++qq) {                                           \
        int rl = (qq * 2 + (tid >> 8)) * 64 + (SET) * 32 + ((tid & 255) >> 3); \
        int jc = (tid & 7) ^ (rl & 7);                                         \
        gl_lds16(W + (size_t)(n0 + rl) * Kc + (KT) + jc * 8,                   \
                 Bs[BUF] + rl * 64 + (tid & 7) * 8);                           \
    } } while (0)

#define G256_LDA(BUF, MQ) do {                                                 \
    _Pragma("unroll")                                                          \
    for (int i = 0; i < 4; ++i) {                                              \
        int row = wm * 128 + (MQ) * 64 + i * 16 + l16;                         \
        const short* rp = As[BUF] + row * 64;                                  \
        _Pragma("unroll")                                                      \
        for (int ks = 0; ks < 2; ++ks)                                         \
            a[i][ks] = *(const bf16x8*)(rp + (((ks * 4 + quad) ^ (row & 7)) << 3)); \
    } } while (0)

#define G256_LDB(BUF, NQ) do {                                                 \
    _Pragma("unroll")                                                          \
    for (int j = 0; j < 2; ++j) {                                              \
        int row = wn * 64 + (NQ) * 32 + j * 16 + l16;                          \
        const short* rp = Bs[BUF] + row * 64;                                  \
        _Pragma("unroll")                                                      \
        for (int ks = 0; ks < 2; ++ks)                                         \
            b[j][ks] = *(const bf16x8*)(rp + (((ks * 4 + quad) ^ (row & 7)) << 3)); \
    } } while (0)

#define G256_MMA(MQ, NQ) do {                                                  \
    __builtin_amdgcn_s_setprio(1);                                             \
    _Pragma("unroll")                                                          \
    for (int i = 0; i < 4; ++i)                                                \
        _Pragma("unroll")                                                      \
        for (int j = 0; j < 2; ++j)                                            \
            _Pragma("unroll")                                                  \
            for (int ks = 0; ks < 2; ++ks)                                     \
                acc[(MQ) * 4 + i][(NQ) * 2 + j] =                              \
                    __builtin_amdgcn_mfma_f32_16x16x32_bf16(                   \
                        a[i][ks], b[j][ks], acc[(MQ) * 4 + i][(NQ) * 2 + j], 0, 0, 0); \
    __builtin_amdgcn_s_setprio(0);                                             \
} while (0)

template<int MODE, typename TC>
__global__ __launch_bounds__(512, 2) void gemm256(const short* __restrict__ A,
        const short* __restrict__ W, const float* __restrict__ bias,
        const bf16* __restrict__ resid, TC* __restrict__ C,
        int Mr, int Nc, int Kc, int ntn)
{
    __shared__ short As[2][256 * 64];   // 64 KB
    __shared__ short Bs[2][256 * 64];   // 64 KB
    const int tid  = threadIdx.x;
    const int lane = tid & 63, wave = tid >> 6;
    const int wm = wave >> 2, wn = wave & 3;           // 2 x 4 wave grid
    const int quad = lane >> 4, l16 = lane & 15;

    // bijective XCD-aware swizzle (m204)
    const int nwg = gridDim.x;
    const int qd = nwg >> 3, rm = nwg & 7;
    const int xcd = blockIdx.x & 7, lin = blockIdx.x >> 3;
    const int wg = (xcd < rm ? xcd * (qd + 1) : rm * (qd + 1) + (xcd - rm) * qd) + lin;
    const int m0 = (wg / ntn) * 256, n0 = (wg % ntn) * 256;

    f32x4 acc[8][4];
#pragma unroll
    for (int i = 0; i < 8; ++i)
#pragma unroll
        for (int j = 0; j < 4; ++j) acc[i][j] = (f32x4){0.f, 0.f, 0.f, 0.f};
    bf16x8 a[4][2], b[2][2];

    const int niter = Kc >> 7;   // K tiles of 128 per iteration (2 x BK=64)

    // prologue: tile0 fully (8 loads) + tile1 {A0,B1} (4 loads, = ph6/ph7 of a
    // virtual previous iteration); vmcnt(4) drains tile0, leaves 4 in flight.
    G256_STAGE_A(0, 0, 0);  G256_STAGE_B(0, 1, 0);
    G256_STAGE_A(0, 1, 0);  G256_STAGE_B(0, 0, 0);
    G256_STAGE_A(1, 0, 64); G256_STAGE_B(1, 1, 64);
    G256_VM4;
    G256_BAR;

    for (int it = 0; it < niter; ++it) {
        const int kT = it * 128;
        const bool pre = (it + 1 < niter);
        // ---- ph0: q(0,0) of tile T (buf0) ----
        G256_LDA(0, 0); G256_LDB(0, 0);
        G256_STAGE_A(1, 1, kT + 64);                 // A1b1(T+1), always valid
        G256_BAR; G256_LGKM0;
        G256_MMA(0, 0);
        // ---- ph1: q(0,1) ----
        G256_LDB(0, 1);
        G256_STAGE_B(1, 0, kT + 64);                 // B0b1(T+1), always valid
        G256_BAR; G256_LGKM0;
        G256_MMA(0, 1);
        // ---- ph2: q(1,1) ----
        G256_LDA(0, 1);
        if (pre) G256_STAGE_A(0, 0, kT + 128);       // A0b0(T+2)
        G256_BAR; G256_LGKM0;
        G256_MMA(1, 1);
        // ---- ph3: q(1,0); half-tile boundary wait ----
        G256_LDB(0, 0);
        if (pre) G256_STAGE_B(0, 1, kT + 128);       // B1b0(T+2)
        if (pre) { G256_VM4; } else { G256_VM0; }    // T+1 buf1 fully landed
        G256_BAR; G256_LGKM0;
        G256_MMA(1, 0);
        // ---- ph4: q(0,0) of tile T+1 (buf1) ----
        G256_LDA(1, 0); G256_LDB(1, 0);
        if (pre) G256_STAGE_A(0, 1, kT + 128);       // A1b0(T+2)
        G256_BAR; G256_LGKM0;
        G256_MMA(0, 0);
        // ---- ph5: q(0,1) ----
        G256_LDB(1, 1);
        if (pre) G256_STAGE_B(0, 0, kT + 128);       // B0b0(T+2)
        G256_BAR; G256_LGKM0;
        G256_MMA(0, 1);
        // ---- ph6: q(1,1) ----
        G256_LDA(1, 1);
        if (pre) G256_STAGE_A(1, 0, kT + 192);       // A0b1(T+3)
        G256_BAR; G256_LGKM0;
        G256_MMA(1, 1);
        // ---- ph7: q(1,0); half-tile boundary wait ----
        G256_LDB(1, 0);
        if (pre) G256_STAGE_B(1, 1, kT + 192);       // B1b1(T+3)
        if (pre) { G256_VM4; } else { G256_VM0; }    // T+2 buf0 fully landed
        G256_BAR; G256_LGKM0;
        G256_MMA(1, 0);
    }

    // Epilogue. C/D layout: col = lane&15, row = quad*4 + reg  [m89/m91 verified]
#pragma unroll
    for (int fm = 0; fm < 8; ++fm)
#pragma unroll
        for (int r = 0; r < 4; ++r) {
            int row = m0 + wm * 128 + fm * 16 + quad * 4 + r;
            if (row >= Mr) continue;
#pragma unroll
            for (int fn = 0; fn < 4; ++fn) {
                int col = n0 + wn * 64 + fn * 16 + l16;
                float v = acc[fm][fn][r] + bias[col];
                if (MODE == 1) v = gelu_exact(v);
                if (MODE == 2) v += b2f(resid[(size_t)row * Nc + col]);
                st1(C + (size_t)row * Nc + col, v);
            }
        }
}

// ---------------- MFMA GEMM (bf16 x bf16): BK=64, XOR-swizzled LDS --------------
// (small/medium GEMMs: 3 blocks/CU -> m114 implicit overlap)
template<int MODE, typename TC>
__global__ __launch_bounds__(256) void gemm_bf(const short* __restrict__ A,
        const short* __restrict__ W, const float* __restrict__ bias,
        const bf16* __restrict__ resid, TC* __restrict__ C,
        int Mr, int Nc, int Kc)
{
    __shared__ short Abuf[128 * 64];   // 16 KB
    __shared__ short Bbuf[128 * 64];   // 16 KB
    const int tid  = threadIdx.x;
    const int lane = tid & 63, wave = tid >> 6;
    const int wm = wave & 1, wn = wave >> 1;
    const int quad = lane >> 4, l16 = lane & 15;
    const int m0 = blockIdx.y * 128, n0 = blockIdx.x * 128;

    f32x4 acc[4][4];
#pragma unroll
    for (int i = 0; i < 4; ++i)
#pragma unroll
        for (int j = 0; j < 4; ++j) acc[i][j] = (f32x4){0.f, 0.f, 0.f, 0.f};

    for (int k0 = 0; k0 < Kc; k0 += 64) {
        __syncthreads();   // prior slab's ds_reads done before LDS overwrite
#pragma unroll
        for (int q = 0; q < 4; ++q) {
            int c = q * 256 + tid;
            int row = c >> 3;
            int j = (c & 7) ^ (row & 7);      // global k-chunk for this LDS slot
            int rowA = m0 + row;
            if (rowA > Mr - 1) rowA = Mr - 1; // clamp tail tile (discarded at store)
            gl_lds16(A + (size_t)rowA * Kc + k0 + j * 8, Abuf + c * 8);
        }
#pragma unroll
        for (int q = 0; q < 4; ++q) {
            int c = q * 256 + tid;
            int row = c >> 3;
            int j = (c & 7) ^ (row & 7);
            gl_lds16(W + (size_t)(n0 + row) * Kc + k0 + j * 8, Bbuf + c * 8);
        }
        __syncthreads();   // drains vmcnt (global_load_lds)
#pragma unroll
        for (int t = 0; t < 2; ++t) {
            bf16x8 fa[4], fb[4];
#pragma unroll
            for (int i = 0; i < 4; ++i) {
                int r = wm * 64 + i * 16 + l16;
                fa[i] = *(const bf16x8*)(Abuf + r * 64 + (((t * 4 + quad) ^ (r & 7)) << 3));
            }
#pragma unroll
            for (int j = 0; j < 4; ++j) {
                int r = wn * 64 + j * 16 + l16;
                fb[j] = *(const bf16x8*)(Bbuf + r * 64 + (((t * 4 + quad) ^ (r & 7)) << 3));
            }
#pragma unroll
            for (int i = 0; i < 4; ++i)
#pragma unroll
                for (int j = 0; j < 4; ++j)
                    acc[i][j] = __builtin_amdgcn_mfma_f32_16x16x32_bf16(fa[i], fb[j], acc[i][j], 0, 0, 0);
        }
    }

    // Epilogue. C/D layout: col = lane&15, row = quad*4 + reg  [m89/m91 verified]
#pragma unroll
    for (int i = 0; i < 4; ++i)
#pragma unroll
        for (int r = 0; r < 4; ++r) {
            int row = m0 + wm * 64 + i * 16 + quad * 4 + r;
            if (row >= Mr) continue;
#pragma unroll
            for (int j = 0; j < 4; ++j) {
                int col = n0 + wn * 64 + j * 16 + l16;
                float v = acc[i][j][r] + bias[col];
                if (MODE == 1) v = gelu_exact(v);
                if (MODE == 2) v += b2f(resid[(size_t)row * Nc + col]);
                st1(C + (size_t)row * Nc + col, v);
            }
        }
}

// ---------------- fallback GEMM (fp32 weights, BK=32, round-6 proven) -----------
template<int MODE, typename TC>
__global__ __launch_bounds__(256) void gemm_f32b(const short* __restrict__ A,
        const float* __restrict__ W, const float* __restrict__ bias,
        const bf16* __restrict__ resid, TC* __restrict__ C,
        int Mr, int Nc, int Kc)
{
    __shared__ short Abuf[128 * 32];
    __shared__ short Bbuf[128 * 32];
    const int tid  = threadIdx.x;
    const int lane = tid & 63, wave = tid >> 6;
    const int wm = wave & 1, wn = wave >> 1;
    const int quad = lane >> 4, l16 = lane & 15;
    const int m0 = blockIdx.y * 128, n0 = blockIdx.x * 128;
    f32x4 acc[4][4];
#pragma unroll
    for (int i = 0; i < 4; ++i)
#pragma unroll
        for (int j = 0; j < 4; ++j) acc[i][j] = (f32x4){0.f, 0.f, 0.f, 0.f};
    const int brow = tid >> 3;
    const int bk   = (tid & 7) * 4;
    for (int k0 = 0; k0 < Kc; k0 += 32) {
        float4 wv[4];
#pragma unroll
        for (int s = 0; s < 4; ++s)
            wv[s] = *(const float4*)(W + (size_t)(n0 + s * 32 + brow) * Kc + k0 + bk);
        __syncthreads();
#pragma unroll
        for (int q = 0; q < 2; ++q) {
            int c = q * 256 + tid;
            int rowA = m0 + (c >> 2);
            if (rowA > Mr - 1) rowA = Mr - 1;
            gl_lds16(A + (size_t)rowA * Kc + k0 + (c & 3) * 8, Abuf + c * 8);
        }
#pragma unroll
        for (int s = 0; s < 4; ++s) {
            short4 h = make_short4(f2bs(wv[s].x), f2bs(wv[s].y), f2bs(wv[s].z), f2bs(wv[s].w));
            *(short4*)(Bbuf + (s * 32 + brow) * 32 + bk) = h;
        }
        __syncthreads();
        bf16x8 fa[4], fb[4];
#pragma unroll
        for (int i = 0; i < 4; ++i)
            fa[i] = *(const bf16x8*)(Abuf + (wm * 64 + i * 16 + l16) * 32 + quad * 8);
#pragma unroll
        for (int j = 0; j < 4; ++j)
            fb[j] = *(const bf16x8*)(Bbuf + (wn * 64 + j * 16 + l16) * 32 + quad * 8);
#pragma unroll
        for (int i = 0; i < 4; ++i)
#pragma unroll
            for (int j = 0; j < 4; ++j)
                acc[i][j] = __builtin_amdgcn_mfma_f32_16x16x32_bf16(fa[i], fb[j], acc[i][j], 0, 0, 0);
    }
#pragma unroll
    for (int i = 0; i < 4; ++i)
#pragma unroll
        for (int r = 0; r < 4; ++r) {
            int row = m0 + wm * 64 + i * 16 + quad * 4 + r;
            if (row >= Mr) continue;
#pragma unroll
            for (int j = 0; j < 4; ++j) {
                int col = n0 + wn * 64 + j * 16 + l16;
                float v = acc[i][j][r] + bias[col];
                if (MODE == 1) v = gelu_exact(v);
                if (MODE == 2) v += b2f(resid[(size_t)row * Nc + col]);
                st1(C + (size_t)row * Nc + col, v);
            }
        }
}

// ---------------- Attention (MFMA): one block per (b,h) ----------------
__global__ __launch_bounds__(256) void attn_mfma(const bf16* __restrict__ qkv,
        bf16* __restrict__ ctx) {
    const int NS = 197;
    const int KST = 104;
    const int VST = 232;
    __shared__ short Kbuf[224 * KST];
    __shared__ short Vt[96 * VST];
    __shared__ short Pbuf[4][16 * VST];
    const int b = blockIdx.x >> 3, h = blockIdx.x & 7;
    const short* base = (const short*)qkv + (size_t)b * NS * 2304 + h * 96;
    const int tid = threadIdx.x;

    for (int c = tid; c < NS * 12; c += 256) {
        int key = c / 12, dc = c % 12;
        bf16x8 v = *(const bf16x8*)(base + (size_t)key * 2304 + 768 + dc * 8);
        *(bf16x8*)(Kbuf + key * KST + dc * 8) = v;
    }
    for (int c = tid; c < 27 * 12; c += 256) {
        int key = NS + c / 12, dc = c % 12;
        *(bf16x8*)(Kbuf + key * KST + dc * 8) = (bf16x8){0, 0, 0, 0, 0, 0, 0, 0};
    }
    for (int c = tid; c < NS * 12; c += 256) {
        int key = c / 12, dc = c % 12;
        bf16x8 v = *(const bf16x8*)(base + (size_t)key * 2304 + 1536 + dc * 8);
#pragma unroll
        for (int j = 0; j < 8; ++j) Vt[(dc * 8 + j) * VST + key] = v[j];
    }
    for (int c = tid; c < 96 * 27; c += 256) {
        int d = c / 27, key = NS + c % 27;
        Vt[d * VST + key] = 0;
    }
    __syncthreads();

    const int wave = tid >> 6, lane = tid & 63;
    const int quad = lane >> 4, l16 = lane & 15;
    short* P = &Pbuf[wave][0];

    for (int qt = wave; qt < 13; qt += 4) {
        int qrow = qt * 16 + l16; if (qrow > NS - 1) qrow = NS - 1;
        bf16x8 fq[3];
#pragma unroll
        for (int kc = 0; kc < 3; ++kc)
            fq[kc] = *(const bf16x8*)(base + (size_t)qrow * 2304 + kc * 32 + quad * 8);
        f32x4 s[14];
#pragma unroll
        for (int nt = 0; nt < 14; ++nt) {
            s[nt] = (f32x4){0.f, 0.f, 0.f, 0.f};
#pragma unroll
            for (int kc = 0; kc < 3; ++kc) {
                bf16x8 fk = *(const bf16x8*)(Kbuf + (nt * 16 + l16) * KST + kc * 32 + quad * 8);
                s[nt] = __builtin_amdgcn_mfma_f32_16x16x32_bf16(fq[kc], fk, s[nt], 0, 0, 0);
            }
        }
        const float sc = 0.10206207261596577f;
        float mx[4] = {-1e30f, -1e30f, -1e30f, -1e30f};
#pragma unroll
        for (int nt = 0; nt < 14; ++nt) {
            bool valid = nt * 16 + l16 < NS;
#pragma unroll
            for (int r = 0; r < 4; ++r) {
                float v = s[nt][r] * sc;
                s[nt][r] = v;
                if (valid) mx[r] = fmaxf(mx[r], v);
            }
        }
#pragma unroll
        for (int m = 1; m < 16; m <<= 1)
#pragma unroll
            for (int r = 0; r < 4; ++r) mx[r] = fmaxf(mx[r], __shfl_xor(mx[r], m, 64));
        float l[4] = {0.f, 0.f, 0.f, 0.f};
#pragma unroll
        for (int nt = 0; nt < 14; ++nt) {
            bool valid = nt * 16 + l16 < NS;
#pragma unroll
            for (int r = 0; r < 4; ++r) {
                float e = valid ? __expf(s[nt][r] - mx[r]) : 0.f;
                l[r] += e;
                P[(quad * 4 + r) * VST + nt * 16 + l16] = f2bs(e);
            }
        }
#pragma unroll
        for (int m = 1; m < 16; m <<= 1)
#pragma unroll
            for (int r = 0; r < 4; ++r) l[r] += __shfl_xor(l[r], m, 64);
        __asm__ volatile("s_waitcnt lgkmcnt(0)" ::: "memory");
        f32x4 o[6];
#pragma unroll
        for (int nt = 0; nt < 6; ++nt) o[nt] = (f32x4){0.f, 0.f, 0.f, 0.f};
#pragma unroll
        for (int kc = 0; kc < 7; ++kc) {
            bf16x8 fp = *(const bf16x8*)(P + l16 * VST + kc * 32 + quad * 8);
#pragma unroll
            for (int nt = 0; nt < 6; ++nt) {
                bf16x8 fv = *(const bf16x8*)(Vt + (nt * 16 + l16) * VST + kc * 32 + quad * 8);
                o[nt] = __builtin_amdgcn_mfma_f32_16x16x32_bf16(fp, fv, o[nt], 0, 0, 0);
            }
        }
        float inv[4];
#pragma unroll
        for (int r = 0; r < 4; ++r) inv[r] = 1.f / l[r];
#pragma unroll
        for (int r = 0; r < 4; ++r) {
            int q = qt * 16 + quad * 4 + r;
            if (q >= NS) continue;
            bf16* orow = ctx + ((size_t)(b * NS + q)) * 768 + h * 96;
#pragma unroll
            for (int nt = 0; nt < 6; ++nt)
                orow[nt * 16 + l16] = __float2bfloat16(o[nt][r] * inv[r]);
        }
    }
}

// ---------------- SO(8) adapter tail: rotate + err + LN + residuals -------------
template<bool OUTER, bool FINAL, bool FLN2>
__global__ __launch_bounds__(256) void adapter_finish(
        const bf16* __restrict__ xp, const bf16* __restrict__ xin,
        const float* __restrict__ xouter, const float* __restrict__ eps,
        const float* __restrict__ scale_p, const float* __restrict__ g,
        const float* __restrict__ bta, bf16* __restrict__ out,
        float* __restrict__ e_acc, float* __restrict__ e_out,
        const float* __restrict__ g2, const float* __restrict__ b2,
        bf16* __restrict__ out2, int Dg)
{
    extern __shared__ float smem[];
    float* y = smem;            // Dg
    float* diff2 = smem + Dg;   // 64
    float* red = diff2 + 64;    // 8 head-norms
    float* r1 = red + 8;        // 4
    float* r2 = red + 12;       // 4
    int row = blockIdx.x;
    int hd = Dg >> 3;           // 96 or 384
    int hd8 = hd >> 3;          // chunks per head
    int n8 = Dg >> 3;
    const bf16* xpr = xp + (size_t)row * Dg;
    const bf16* xir = xin + (size_t)row * Dg;
    int tid = threadIdx.x;
    if (tid < 64) {
        int hh = tid >> 3, i = tid & 7, p = i >> 1;
        float ang = eps[((size_t)row * 8 + hh) * 4 + p] * scale_p[0];
        float c = cosf(ang), sn = sinf(ang);
        int base = hh * hd;
        float ev = b2f(xpr[base + 2 * p]), od = b2f(xpr[base + 2 * p + 1]);
        float r = (i & 1) ? (ev * sn + od * c) : (ev * c - od * sn);
        float d = r - b2f(xpr[base + i]);
        diff2[tid] = d * d;
        y[base + i] = r + b2f(xir[base + i]);
    }
    for (int c8 = tid; c8 < n8; c8 += 256) {
        if (c8 % hd8 == 0) continue;   // rot chunk: handled above
        float a[8], bvx[8];
        b8f(*(const bf16x8*)(xpr + c8 * 8), a);
        b8f(*(const bf16x8*)(xir + c8 * 8), bvx);
#pragma unroll
        for (int j = 0; j < 8; ++j) y[c8 * 8 + j] = a[j] + bvx[j];
    }
    __syncthreads();
    if (tid < 8) {
        float t = 0.f;
#pragma unroll
        for (int i = 0; i < 8; ++i) t += diff2[tid * 8 + i];
        red[tid] = sqrtf(t);
    }
    float s = 0.f, s2 = 0.f;
    for (int c = tid; c < Dg; c += 256) { float v = y[c]; s += v; s2 += v * v; }
    for (int off = 32; off; off >>= 1) { s += __shfl_down(s, off, 64); s2 += __shfl_down(s2, off, 64); }
    if ((tid & 63) == 0) { r1[tid >> 6] = s; r2[tid >> 6] = s2; }
    __syncthreads();
    s  = r1[0] + r1[1] + r1[2] + r1[3];
    s2 = r2[0] + r2[1] + r2[2] + r2[3];
    float mean = s / Dg;
    float rstd = rsqrtf(s2 / Dg - mean * mean + 1e-5f);
    if (tid == 0) {
        float e = (red[0] + red[1] + red[2] + red[3] + red[4] + red[5] + red[6] + red[7]) * 0.125f;
        if (FINAL) e_out[row] = e_acc[row] + e;
        else       e_acc[row] = e;
    }
    bf16* outr = out + (size_t)row * Dg;
    const float4* g4 = (const float4*)g;
    const float4* bt4 = (const float4*)bta;
    const float4* xo4 = OUTER ? (const float4*)(xouter + (size_t)row * Dg) : nullptr;
    float sB = 0.f, sB2 = 0.f;
    for (int c8 = tid; c8 < n8; c8 += 256) {
        float xi[8];
        b8f(*(const bf16x8*)(xir + c8 * 8), xi);
        float4 gg0 = g4[c8 * 2], gg1 = g4[c8 * 2 + 1];
        float4 bb0 = bt4[c8 * 2], bb1 = bt4[c8 * 2 + 1];
        float gv[8] = {gg0.x, gg0.y, gg0.z, gg0.w, gg1.x, gg1.y, gg1.z, gg1.w};
        float bv[8] = {bb0.x, bb0.y, bb0.z, bb0.w, bb1.x, bb1.y, bb1.z, bb1.w};
        float vv[8];
#pragma unroll
        for (int j = 0; j < 8; ++j)
            vv[j] = (y[c8 * 8 + j] - mean) * rstd * gv[j] + bv[j] + xi[j];
        if (OUTER) {
            float4 o0 = xo4[c8 * 2], o1 = xo4[c8 * 2 + 1];
            float ov[8] = {o0.x, o0.y, o0.z, o0.w, o1.x, o1.y, o1.z, o1.w};
#pragma unroll
            for (int j = 0; j < 8; ++j) vv[j] += ov[j];
        }
        *(bf16x8*)(outr + c8 * 8) = f8b(vv);
        if (FLN2) {
#pragma unroll
            for (int j = 0; j < 8; ++j) {
                y[c8 * 8 + j] = vv[j];
                sB += vv[j]; sB2 += vv[j] * vv[j];
            }
        }
    }
    if (FLN2) {
        __syncthreads();   // all reads of r1/r2 and y done
        for (int off = 32; off; off >>= 1) { sB += __shfl_down(sB, off, 64); sB2 += __shfl_down(sB2, off, 64); }
        if ((tid & 63) == 0) { r1[tid >> 6] = sB; r2[tid >> 6] = sB2; }
        __syncthreads();
        sB  = r1[0] + r1[1] + r1[2] + r1[3];
        sB2 = r2[0] + r2[1] + r2[2] + r2[3];
        float mean2 = sB / Dg;
        float rstd2 = rsqrtf(sB2 / Dg - mean2 * mean2 + 1e-5f);
        bf16* o2r = out2 + (size_t)row * Dg;
        const float4* g24 = (const float4*)g2;
        const float4* b24 = (const float4*)b2;
        for (int c8 = tid; c8 < n8; c8 += 256) {
            float4 gg0 = g24[c8 * 2], gg1 = g24[c8 * 2 + 1];
            float4 bb0 = b24[c8 * 2], bb1 = b24[c8 * 2 + 1];
            float gv[8] = {gg0.x, gg0.y, gg0.z, gg0.w, gg1.x, gg1.y, gg1.z, gg1.w};
            float bv[8] = {bb0.x, bb0.y, bb0.z, bb0.w, bb1.x, bb1.y, bb1.z, bb1.w};
            float vv[8];
#pragma unroll
            for (int j = 0; j < 8; ++j)
                vv[j] = (y[c8 * 8 + j] - mean2) * rstd2 * gv[j] + bv[j];
            *(bf16x8*)(o2r + c8 * 8) = f8b(vv);
        }
    }
}

extern "C" void kernel_launch(void* const* d_in, const int* in_sizes, int n_in,
                              void* d_out, int out_size, void* d_ws, size_t ws_size,
                              hipStream_t stream) {
    (void)in_sizes; (void)n_in; (void)out_size;
    const int M = MROWS;
    const size_t S_D = (size_t)M * DMODEL;
    const size_t S_H = (size_t)M * DHID;

    const float* x      = (const float*)d_in[0];
    const float* qkv_w  = (const float*)d_in[1];
    const float* qkv_b  = (const float*)d_in[2];
    const float* proj_w = (const float*)d_in[3];
    const float* proj_b = (const float*)d_in[4];
    const float* n1g    = (const float*)d_in[5];
    const float* n1b    = (const float*)d_in[6];
    const float* n2g    = (const float*)d_in[7];
    const float* n2b    = (const float*)d_in[8];
    const float* wa     = (const float*)d_in[9];
    const float* ba     = (const float*)d_in[10];
    const float* sca    = (const float*)d_in[11];
    const float* lga    = (const float*)d_in[12];
    const float* lba    = (const float*)d_in[13];
    const float* wm     = (const float*)d_in[14];
    const float* bm     = (const float*)d_in[15];
    const float* scm    = (const float*)d_in[16];
    const float* lgm    = (const float*)d_in[17];
    const float* lbm    = (const float*)d_in[18];
    const float* f1w    = (const float*)d_in[19];
    const float* f1b    = (const float*)d_in[20];
    const float* f2w    = (const float*)d_in[21];
    const float* f2b    = (const float*)d_in[22];
    const float* eps_a  = (const float*)d_in[23];
    const float* eps_m  = (const float*)d_in[24];

    float* out_x = (float*)d_out;          // M*768 fp32
    float* out_e = out_x + S_D;            // M fp32 (e1+e2)

    bf16* R1 = (bf16*)d_ws;
    bf16* R2 = R1 + S_H;
    bf16* R3 = R2 + S_H;
    float* E = (float*)(R3 + S_D);

    const size_t n_qkv = (size_t)2304 * 768, n_proj = (size_t)768 * 768,
                 n_wa = (size_t)768 * 768, n_wm = (size_t)3072 * 3072,
                 n_f1 = (size_t)3072 * 768, n_f2 = (size_t)768 * 3072;
    const size_t base_bytes = (2 * S_H + S_D) * 2 + (size_t)M * 4;
    const size_t w_elems = n_qkv + n_proj + n_wa + n_wm + n_f1 + n_f2;
    const bool cache_w = ws_size >= base_bytes + w_elems * 2;

    short* WB    = (short*)((char*)d_ws + base_bytes);
    short* wb_qkv = WB;
    short* wb_proj = wb_qkv + n_qkv;
    short* wb_wa  = wb_proj + n_proj;
    short* wb_wm  = wb_wa + n_wa;
    short* wb_f1  = wb_wm + n_wm;
    short* wb_f2  = wb_f1 + n_f1;

    const int GY = (M + 127) / 128;     // 99
    const int GY256 = (M + 255) / 256;  // 50
    const size_t lds_a = (DMODEL + 96) * sizeof(float);
    const size_t lds_m = (DHID + 96) * sizeof(float);

    if (cache_w) {
        cvt_all_kernel<<<(4276224 + 255) / 256, 256, 0, stream>>>(
            qkv_w, proj_w, wa, wm, f1w, f2w, WB);
        ln1_kernel<<<M, 256, 0, stream>>>(x, n1g, n1b, R1, DMODEL);
        gemm_bf<0, bf16><<<dim3(2304 / 128, GY), 256, 0, stream>>>(
            (const short*)R1, wb_qkv, qkv_b, nullptr, R2, M, 2304, DMODEL);
        attn_mfma<<<64 * 8, 256, 0, stream>>>(R2, R1);
        gemm_bf<0, bf16><<<dim3(DMODEL / 128, GY), 256, 0, stream>>>(
            (const short*)R1, wb_proj, proj_b, nullptr, R2, M, DMODEL, DMODEL);
        gemm_bf<0, bf16><<<dim3(DMODEL / 128, GY), 256, 0, stream>>>(
            (const short*)R2, wb_wa, ba, nullptr, R1, M, DMODEL, DMODEL);
        // adapter-A + fused LN2: x_new -> R3, LN2(x_new) -> R2, e1 -> E
        adapter_finish<true, false, true><<<M, 256, lds_a, stream>>>(
            R1, R2, x, eps_a, sca, lga, lba, R3, E, nullptr, n2g, n2b, R2, DMODEL);
        gemm_bf<1, bf16><<<dim3(DHID / 128, GY), 256, 0, stream>>>(
            (const short*)R2, wb_f1, f1b, nullptr, R1, M, DHID, DMODEL);
        gemm256<0, bf16><<<dim3((DHID / 256) * GY256), 512, 0, stream>>>(
            (const short*)R1, wb_wm, bm, nullptr, R2, M, DHID, DHID, DHID / 256);
        adapter_finish<false, true, false><<<M, 256, lds_m, stream>>>(
            R2, R1, nullptr, eps_m, scm, lgm, lbm, R1, E, out_e, nullptr, nullptr, nullptr, DHID);
        gemm_bf<2, float><<<dim3(DMODEL / 128, GY), 256, 0, stream>>>(
            (const short*)R1, wb_f2, f2b, R3, out_x, M, DMODEL, DHID);
    } else {
        ln1_kernel<<<M, 256, 0, stream>>>(x, n1g, n1b, R1, DMODEL);
        gemm_f32b<0, bf16><<<dim3(2304 / 128, GY), 256, 0, stream>>>(
            (const short*)R1, qkv_w, qkv_b, nullptr, R2, M, 2304, DMODEL);
        attn_mfma<<<64 * 8, 256, 0, stream>>>(R2, R1);
        gemm_f32b<0, bf16><<<dim3(DMODEL / 128, GY), 256, 0, stream>>>(
            (const short*)R1, proj_w, proj_b, nullptr, R2, M, DMODEL, DMODEL);
        gemm_f32b<0, bf16><<<dim3(DMODEL / 128, GY), 256, 0, stream>>>(
            (const short*)R2, wa, ba, nullptr, R1, M, DMODEL, DMODEL);
        adapter_finish<true, false, true><<<M, 256, lds_a, stream>>>(
            R1, R2, x, eps_a, sca, lga, lba, R3, E, nullptr, n2g, n2b, R2, DMODEL);
        gemm_f32b<1, bf16><<<dim3(DHID / 128, GY), 256, 0, stream>>>(
            (const short*)R2, f1w, f1b, nullptr, R1, M, DHID, DMODEL);
        gemm_f32b<0, bf16><<<dim3(DHID / 128, GY), 256, 0, stream>>>(
            (const short*)R1, wm, bm, nullptr, R2, M, DHID, DHID);
        adapter_finish<false, true, false><<<M, 256, lds_m, stream>>>(
            R2, R1, nullptr, eps_m, scm, lgm, lbm, R1, E, out_e, nullptr, nullptr, nullptr, DHID);
        gemm_f32b<2, float><<<dim3(DMODEL / 128, GY), 256, 0, stream>>>(
            (const short*)R1, f2w, f2b, R3, out_x, M, DMODEL, DHID);
    }
}